// Round 1
// baseline (1330.374 us; speedup 1.0000x reference)
//
#include <hip/hip_runtime.h>
#include <stdint.h>

typedef __bf16 bf16x8 __attribute__((ext_vector_type(8)));
typedef float f32x4 __attribute__((ext_vector_type(4)));
typedef unsigned short u16;
typedef u16 ushort8 __attribute__((ext_vector_type(8)));

__device__ __forceinline__ u16 f2bf(float f) {
    uint32_t u = __builtin_bit_cast(uint32_t, f);
    u += 0x7FFFu + ((u >> 16) & 1u);   // RNE, inputs finite
    return (u16)(u >> 16);
}

__device__ __forceinline__ void gload16(const void* g, void* l) {
    __builtin_amdgcn_global_load_lds(
        reinterpret_cast<const __attribute__((address_space(1))) void*>(reinterpret_cast<uintptr_t>(g)),
        reinterpret_cast<__attribute__((address_space(3))) void*>(reinterpret_cast<uintptr_t>(l)),
        16, 0, 0);
}

// ---------------------------------------------------------------------------
// GEMM: C[M,NN] = A[M,K] @ B[NN,K]^T   (A,B bf16 row-major, K contiguous)
// 128x128 tile, BK=32, 256 threads = 4 waves (2x2), 64x64 per wave,
// mfma_f32_16x16x32_bf16, global_load_lds staging (m97 structure).
// MODE 0: Abuf bf16 store: C = f2bf(wrow[r]*silu(acc + bias[c]))
// MODE 1: f32 store:  C = acc
// MODE 2: f32 accum:  C += acc
// ---------------------------------------------------------------------------
#define BM 128
#define BN 128
#define BK 32

template <int MODE>
__global__ __launch_bounds__(256)
void gemm_bt(const u16* __restrict__ A, int lda,
             const u16* __restrict__ B, int ldb,
             int K,
             void* __restrict__ Cout, int ldc,
             const float* __restrict__ bias,
             const float* __restrict__ wrow, int wstride)
{
    __shared__ __align__(16) u16 As[BM * BK];
    __shared__ __align__(16) u16 Bs[BN * BK];

    const int t    = threadIdx.x;
    const int wave = t >> 6;
    const int lane = t & 63;
    const int l16  = lane & 15;
    const int lhi  = lane >> 4;
    const int wm   = wave >> 1;
    const int wn   = wave & 1;

    const size_t rowBase = (size_t)blockIdx.y * BM;
    const int    colBase = blockIdx.x * BN;

    // staging: chunk c = i*256 + t covers 16B at As[c*8]; row = c>>2, kq = (c&3)*8
    const int arow = t >> 2;
    const int kq   = (t & 3) * 8;
    const u16* aSrc0 = A + (rowBase + arow)       * (size_t)lda + kq;
    const u16* aSrc1 = A + (rowBase + arow + 64)  * (size_t)lda + kq;
    const u16* bSrc0 = B + (size_t)(colBase + arow)      * ldb + kq;
    const u16* bSrc1 = B + (size_t)(colBase + arow + 64) * ldb + kq;
    u16* aDst0 = &As[(wave * 64) * 8];         // wave-uniform LDS base; HW adds lane*16B
    u16* aDst1 = &As[(256 + wave * 64) * 8];
    u16* bDst0 = &Bs[(wave * 64) * 8];
    u16* bDst1 = &Bs[(256 + wave * 64) * 8];

    f32x4 acc[4][4];
#pragma unroll
    for (int i = 0; i < 4; i++)
#pragma unroll
        for (int j = 0; j < 4; j++)
            acc[i][j] = (f32x4){0.f, 0.f, 0.f, 0.f};

    for (int kt = 0; kt < K; kt += BK) {
        gload16(aSrc0 + kt, aDst0);
        gload16(aSrc1 + kt, aDst1);
        gload16(bSrc0 + kt, bDst0);
        gload16(bSrc1 + kt, bDst1);
        __syncthreads();   // compiler drains vmcnt(0) before s_barrier

        bf16x8 af[4], bfv[4];
#pragma unroll
        for (int mi = 0; mi < 4; mi++)
            af[mi] = *(const bf16x8*)&As[(wm * 64 + mi * 16 + l16) * BK + lhi * 8];
#pragma unroll
        for (int ni = 0; ni < 4; ni++)
            bfv[ni] = *(const bf16x8*)&Bs[(wn * 64 + ni * 16 + l16) * BK + lhi * 8];

#pragma unroll
        for (int mi = 0; mi < 4; mi++)
#pragma unroll
            for (int ni = 0; ni < 4; ni++)
                acc[mi][ni] = __builtin_amdgcn_mfma_f32_16x16x32_bf16(
                    af[mi], bfv[ni], acc[mi][ni], 0, 0, 0);

        __syncthreads();
    }

    const int orow0 = wm * 64 + lhi * 4;   // + mi*16 + j
    const int ocol0 = colBase + wn * 64 + l16;

    if constexpr (MODE == 0) {
        u16* C = (u16*)Cout;
#pragma unroll
        for (int mi = 0; mi < 4; mi++) {
#pragma unroll
            for (int j = 0; j < 4; j++) {
                size_t r = rowBase + orow0 + mi * 16 + j;
                float w = wrow[r * (size_t)wstride];
#pragma unroll
                for (int ni = 0; ni < 4; ni++) {
                    int c = ocol0 + ni * 16;
                    float v = acc[mi][ni][j] + bias[c];
                    float s = v / (1.f + __expf(-v));   // silu
                    C[r * (size_t)ldc + c] = f2bf(w * s);
                }
            }
        }
    } else {
        float* C = (float*)Cout;
#pragma unroll
        for (int mi = 0; mi < 4; mi++) {
#pragma unroll
            for (int j = 0; j < 4; j++) {
                size_t r = rowBase + orow0 + mi * 16 + j;
#pragma unroll
                for (int ni = 0; ni < 4; ni++) {
                    size_t idx = r * (size_t)ldc + (ocol0 + ni * 16);
                    if constexpr (MODE == 1) C[idx] = acc[mi][ni][j];
                    else                     C[idx] += acc[mi][ni][j];
                }
            }
        }
    }
}

// ---------------------------------------------------------------------------
// Router: logits[r][0..79] = x[r] . {Wsoft(5) | Wsparse(5) | m_key(64) | Wg(5)}
// f32 (argmax must match the f32 reference). 64 rows/block, 256 threads.
// ---------------------------------------------------------------------------
__global__ __launch_bounds__(256)
void router_kernel(const float* __restrict__ x,
                   const float* __restrict__ Wsoft, const float* __restrict__ Wsparse,
                   const float* __restrict__ m_key, const float* __restrict__ Wg,
                   float* __restrict__ logits)
{
    __shared__ float Xs[128][66];    // [k][row], padded
    __shared__ float Ws[80][132];    // [j][k],  padded

    const int t    = threadIdx.x;
    const int lane = t & 63;
    const int wave = t >> 6;
    const int row0 = blockIdx.x * 64;

    float acc[20];
#pragma unroll
    for (int c = 0; c < 20; c++) acc[c] = 0.f;

    for (int k0 = 0; k0 < 1024; k0 += 128) {
        // stage X: 64x128 = 2048 float4, 8/thread (transposed into Xs)
#pragma unroll
        for (int i = 0; i < 8; i++) {
            int f4 = i * 256 + t;
            int r  = f4 >> 5;
            int kk = (f4 & 31) * 4;
            f32x4 v = *(const f32x4*)(x + (size_t)(row0 + r) * 1024 + k0 + kk);
            Xs[kk + 0][r] = v[0]; Xs[kk + 1][r] = v[1];
            Xs[kk + 2][r] = v[2]; Xs[kk + 3][r] = v[3];
        }
        // stage W: 80x128 = 2560 float4, 10/thread
#pragma unroll
        for (int i = 0; i < 10; i++) {
            int f4 = i * 256 + t;
            int j  = f4 >> 5;
            int kk = (f4 & 31) * 4;
            const float* src;
            if      (j < 5)  src = Wsoft   + (size_t)j * 1024;
            else if (j < 10) src = Wsparse + (size_t)(j - 5) * 1024;
            else if (j < 74) src = m_key   + (size_t)(j - 10) * 1024;
            else             src = Wg      + (size_t)(j - 74) * 1024;
            *(f32x4*)&Ws[j][kk] = *(const f32x4*)(src + k0 + kk);
        }
        __syncthreads();

        for (int k4 = 0; k4 < 32; k4++) {
            float x0 = Xs[k4 * 4 + 0][lane];
            float x1 = Xs[k4 * 4 + 1][lane];
            float x2 = Xs[k4 * 4 + 2][lane];
            float x3 = Xs[k4 * 4 + 3][lane];
#pragma unroll
            for (int c = 0; c < 20; c++) {
                f32x4 w = *(const f32x4*)&Ws[wave * 20 + c][k4 * 4];
                acc[c] += x0 * w[0] + x1 * w[1] + x2 * w[2] + x3 * w[3];
            }
        }
        __syncthreads();
    }

    float* dst = logits + (size_t)(row0 + lane) * 80 + wave * 20;
#pragma unroll
    for (int c = 0; c < 20; c++) dst[c] = acc[c];
}

// ---------------------------------------------------------------------------
// Finalize: per-row softmaxes / top-1 / memory attention -> fw05, g05
// fw05 = 0.5*final_w = 0.125*sparse + 0.125*soft + 0.25*mem ; g05 = 0.5*sigmoid
// ---------------------------------------------------------------------------
__global__ __launch_bounds__(256)
void finalize_kernel(const float* __restrict__ logits, const float* __restrict__ m_val,
                     const float* __restrict__ bsoft, const float* __restrict__ bsparse,
                     const float* __restrict__ bg,
                     float* __restrict__ fw05, float* __restrict__ g05, int NC)
{
    __shared__ float mv[320];
    for (int i = threadIdx.x; i < 320; i += 256) mv[i] = m_val[i];
    __syncthreads();

    int idx = blockIdx.x * 256 + threadIdx.x;
    if (idx >= NC) return;
    const float* L = logits + (size_t)idx * 80;

    // soft router softmax
    float sl[5];
#pragma unroll
    for (int e = 0; e < 5; e++) sl[e] = L[e] + bsoft[e];
    float sm = sl[0];
#pragma unroll
    for (int e = 1; e < 5; e++) sm = fmaxf(sm, sl[e]);
    float ssum = 0.f, sw[5];
#pragma unroll
    for (int e = 0; e < 5; e++) { sw[e] = __expf(sl[e] - sm); ssum += sw[e]; }
    float sinv = 1.f / ssum;

    // sparse top-1 (ties -> lowest index, strict >)
    int am = 0; float bv = L[5] + bsparse[0];
#pragma unroll
    for (int e = 1; e < 5; e++) {
        float v = L[5 + e] + bsparse[e];
        if (v > bv) { bv = v; am = e; }
    }

    // memory attention: softmax over 64 of (dot/32), then @ m_val, then softmax
    float amax = -1e30f;
    for (int m = 0; m < 64; m++) amax = fmaxf(amax, L[10 + m] * 0.03125f);
    float asum = 0.f, mw[5] = {0.f, 0.f, 0.f, 0.f, 0.f};
    for (int m = 0; m < 64; m++) {
        float a = __expf(L[10 + m] * 0.03125f - amax);
        asum += a;
#pragma unroll
        for (int e = 0; e < 5; e++) mw[e] += a * mv[m * 5 + e];
    }
    float ainv = 1.f / asum;
#pragma unroll
    for (int e = 0; e < 5; e++) mw[e] *= ainv;
    float mm = mw[0];
#pragma unroll
    for (int e = 1; e < 5; e++) mm = fmaxf(mm, mw[e]);
    float msum = 0.f, me[5];
#pragma unroll
    for (int e = 0; e < 5; e++) { me[e] = __expf(mw[e] - mm); msum += me[e]; }
    float minv = 1.f / msum;

#pragma unroll
    for (int e = 0; e < 5; e++)
        fw05[(size_t)idx * 5 + e] =
            0.125f * ((e == am) ? 1.f : 0.f) + 0.125f * sw[e] * sinv + 0.25f * me[e] * minv;
#pragma unroll
    for (int q = 0; q < 5; q++)
        g05[(size_t)idx * 5 + q] = 0.5f / (1.f + __expf(-(L[74 + q] + bg[q])));
}

// ---------------------------------------------------------------------------
// Elementwise f32 -> bf16 cast (n multiple of 8)
// ---------------------------------------------------------------------------
__global__ __launch_bounds__(256)
void cast_bf16_kernel(const float* __restrict__ src, u16* __restrict__ dst, size_t n)
{
    size_t i = ((size_t)blockIdx.x * 256 + threadIdx.x) * 8;
    if (i >= n) return;
    f32x4 a = *(const f32x4*)(src + i);
    f32x4 b = *(const f32x4*)(src + i + 4);
    ushort8 o;
    o[0] = f2bf(a[0]); o[1] = f2bf(a[1]); o[2] = f2bf(a[2]); o[3] = f2bf(a[3]);
    o[4] = f2bf(b[0]); o[5] = f2bf(b[1]); o[6] = f2bf(b[2]); o[7] = f2bf(b[3]);
    *(ushort8*)(dst + i) = o;
}

// ---------------------------------------------------------------------------
// W2cat[o][c], c<5120: W2[e][o][d] (e=c>>10,d=c&1023); c=5120+e: b2[e][o]; else 0
// ---------------------------------------------------------------------------
__global__ __launch_bounds__(256)
void prep_w2cat(const float* __restrict__ W2, const float* __restrict__ b2,
                u16* __restrict__ out)
{
    size_t tid = (size_t)blockIdx.x * 256 + threadIdx.x;   // 1024*644 threads
    int o  = (int)(tid / 644);
    int c0 = (int)(tid % 644) * 8;
    ushort8 v;
    if (c0 + 8 <= 5120) {
        int e = c0 >> 10, d = c0 & 1023;
        const float* s = W2 + ((size_t)e * 1024 + o) * 1024 + d;
        f32x4 a = *(const f32x4*)s;
        f32x4 b = *(const f32x4*)(s + 4);
        v[0] = f2bf(a[0]); v[1] = f2bf(a[1]); v[2] = f2bf(a[2]); v[3] = f2bf(a[3]);
        v[4] = f2bf(b[0]); v[5] = f2bf(b[1]); v[6] = f2bf(b[2]); v[7] = f2bf(b[3]);
    } else {
#pragma unroll
        for (int jj = 0; jj < 8; jj++) {
            int c = c0 + jj;
            float f = (c >= 5120 && c < 5125) ? b2[(size_t)(c - 5120) * 1024 + o] : 0.f;
            v[jj] = f2bf(f);
        }
    }
    *(ushort8*)(out + (size_t)o * 5152 + c0) = v;
}

// Wfcat[o][c], c<5120: Wf[o][c]; c==5120: bf[o]; else 0
__global__ __launch_bounds__(256)
void prep_wfcat(const float* __restrict__ Wf, const float* __restrict__ bfias,
                u16* __restrict__ out)
{
    size_t tid = (size_t)blockIdx.x * 256 + threadIdx.x;
    int o  = (int)(tid / 644);
    int c0 = (int)(tid % 644) * 8;
    ushort8 v;
    if (c0 + 8 <= 5120) {
        const float* s = Wf + (size_t)o * 5120 + c0;
        f32x4 a = *(const f32x4*)s;
        f32x4 b = *(const f32x4*)(s + 4);
        v[0] = f2bf(a[0]); v[1] = f2bf(a[1]); v[2] = f2bf(a[2]); v[3] = f2bf(a[3]);
        v[4] = f2bf(b[0]); v[5] = f2bf(b[1]); v[6] = f2bf(b[2]); v[7] = f2bf(b[3]);
    } else {
#pragma unroll
        for (int jj = 0; jj < 8; jj++) {
            int c = c0 + jj;
            v[jj] = f2bf((c == 5120) ? bfias[o] : 0.f);
        }
    }
    *(ushort8*)(out + (size_t)o * 5152 + c0) = v;
}

// Abuf[r][c] = bf16(g05[r,q] * feat_q[r][d])  for c<5120
__global__ __launch_bounds__(256)
void build_afused(const float* __restrict__ f0, const float* __restrict__ f1,
                  const float* __restrict__ f2, const float* __restrict__ f3,
                  const float* __restrict__ f4,
                  const float* __restrict__ g05, u16* __restrict__ Abuf)
{
    size_t tid = (size_t)blockIdx.x * 256 + threadIdx.x;   // NC*640 threads
    size_t r  = tid / 640;
    int   cb  = (int)(tid % 640);
    int   c0  = cb * 8;
    int   q   = c0 >> 10;
    int   d   = c0 & 1023;
    const float* fq = (q == 0) ? f0 : (q == 1) ? f1 : (q == 2) ? f2 : (q == 3) ? f3 : f4;
    float g = g05[r * 5 + q];
    f32x4 a = *(const f32x4*)(fq + r * 1024 + d);
    f32x4 b = *(const f32x4*)(fq + r * 1024 + d + 4);
    ushort8 v;
    v[0] = f2bf(g * a[0]); v[1] = f2bf(g * a[1]); v[2] = f2bf(g * a[2]); v[3] = f2bf(g * a[3]);
    v[4] = f2bf(g * b[0]); v[5] = f2bf(g * b[1]); v[6] = f2bf(g * b[2]); v[7] = f2bf(g * b[3]);
    *(ushort8*)(Abuf + r * 5152 + c0) = v;
}

// Tail cols 5120..5151. mode 0 (MOE): fw05[r,e] at 5120+e. mode 1 (FUSE): 0.5 at 5120.
__global__ __launch_bounds__(256)
void fill_tail(const float* __restrict__ fw05, u16* __restrict__ Abuf, int NC, int mode)
{
    int r = blockIdx.x * 256 + threadIdx.x;
    if (r >= NC) return;
    u16* dst = Abuf + (size_t)r * 5152 + 5120;
    if (mode == 0) {
#pragma unroll
        for (int e = 0; e < 5; e++) dst[e] = f2bf(fw05[(size_t)r * 5 + e]);
        for (int j = 5; j < 32; j++) dst[j] = 0;
    } else {
        dst[0] = f2bf(0.5f);
        for (int j = 1; j < 32; j++) dst[j] = 0;
    }
}

// ---------------------------------------------------------------------------
extern "C" void kernel_launch(void* const* d_in, const int* in_sizes, int n_in,
                              void* d_out, int out_size, void* d_ws, size_t ws_size,
                              hipStream_t stream)
{
    (void)in_sizes; (void)n_in; (void)out_size;

    const float* x      = (const float*)d_in[0];
    const float* spect  = (const float*)d_in[1];
    const float* wavef  = (const float*)d_in[2];
    const float* pitch  = (const float*)d_in[3];
    const float* envel  = (const float*)d_in[4];
    const float* phase  = (const float*)d_in[5];
    const float* Wsoft  = (const float*)d_in[6];
    const float* bsoft  = (const float*)d_in[7];
    const float* Wsparse= (const float*)d_in[8];
    const float* bsparse= (const float*)d_in[9];
    const float* m_key  = (const float*)d_in[10];
    const float* m_val  = (const float*)d_in[11];
    const float* W1     = (const float*)d_in[12];
    const float* b1     = (const float*)d_in[13];
    const float* W2     = (const float*)d_in[14];
    const float* b2     = (const float*)d_in[15];
    const float* Wg     = (const float*)d_in[16];
    const float* bg     = (const float*)d_in[17];
    const float* Wf     = (const float*)d_in[18];
    const float* bfias  = (const float*)d_in[19];
    float* out = (float*)d_out;

    const int N = 16384;

    // workspace layout
    size_t fixed = (size_t)5 * 1024 * 1024 * 2 + 2 * (size_t)1024 * 5152 * 2;
    int NC = 16384;
    while (NC > 128 && fixed + (size_t)NC * 12712 > ws_size) NC >>= 1;

    char* p = (char*)d_ws;
    u16* W1bf  = (u16*)p; p += (size_t)5 * 1024 * 1024 * 2;
    u16* W2cat = (u16*)p; p += (size_t)1024 * 5152 * 2;
    u16* Wfcat = (u16*)p; p += (size_t)1024 * 5152 * 2;
    u16* Xbf   = (u16*)p; p += (size_t)NC * 1024 * 2;
    u16* Abuf  = (u16*)p; p += (size_t)NC * 5152 * 2;
    float* logits = (float*)p; p += (size_t)NC * 80 * 4;
    float* fw05   = (float*)p; p += (size_t)NC * 5 * 4;
    float* g05    = (float*)p; p += (size_t)NC * 5 * 4;

    // one-time weight prep
    cast_bf16_kernel<<<2560, 256, 0, stream>>>(W1, W1bf, (size_t)5 * 1024 * 1024);
    prep_w2cat<<<2576, 256, 0, stream>>>(W2, b2, W2cat);
    prep_wfcat<<<2576, 256, 0, stream>>>(Wf, bfias, Wfcat);

    for (int n0 = 0; n0 < N; n0 += NC) {
        const float* xc = x + (size_t)n0 * 1024;

        router_kernel<<<NC / 64, 256, 0, stream>>>(xc, Wsoft, Wsparse, m_key, Wg, logits);
        finalize_kernel<<<(NC + 255) / 256, 256, 0, stream>>>(logits, m_val, bsoft, bsparse, bg,
                                                              fw05, g05, NC);
        cast_bf16_kernel<<<NC / 2, 256, 0, stream>>>(xc, Xbf, (size_t)NC * 1024);

        // expert hidden layers -> Abuf cols [e*1024, e*1024+1024)
        for (int e = 0; e < 5; e++) {
            gemm_bt<0><<<dim3(8, NC / 128), 256, 0, stream>>>(
                Xbf, 1024,
                W1bf + (size_t)e * 1024 * 1024, 1024,
                1024,
                Abuf + (size_t)e * 1024, 5152,
                b1 + (size_t)e * 1024,
                fw05 + e, 5);
        }
        fill_tail<<<(NC + 255) / 256, 256, 0, stream>>>(fw05, Abuf, NC, 0);

        // 0.5*moe -> out
        gemm_bt<1><<<dim3(8, NC / 128), 256, 0, stream>>>(
            Abuf, 5152, W2cat, 5152, 5152,
            out + (size_t)n0 * 1024, 1024, nullptr, nullptr, 0);

        // gated features -> Abuf
        build_afused<<<(unsigned)((size_t)NC * 640 / 256), 256, 0, stream>>>(
            spect + (size_t)n0 * 1024, wavef + (size_t)n0 * 1024,
            pitch + (size_t)n0 * 1024, envel + (size_t)n0 * 1024,
            phase + (size_t)n0 * 1024, g05, Abuf);
        fill_tail<<<(NC + 255) / 256, 256, 0, stream>>>(fw05, Abuf, NC, 1);

        // out += 0.5*fused
        gemm_bt<2><<<dim3(8, NC / 128), 256, 0, stream>>>(
            Abuf, 5152, Wfcat, 5152, 5152,
            out + (size_t)n0 * 1024, 1024, nullptr, nullptr, 0);
    }
}

// Round 2
// 850.869 us; speedup vs baseline: 1.5635x; 1.5635x over previous
//
#include <hip/hip_runtime.h>
#include <stdint.h>

typedef __bf16 bf16x8 __attribute__((ext_vector_type(8)));
typedef float f32x4 __attribute__((ext_vector_type(4)));
typedef unsigned short u16;
typedef u16 ushort8 __attribute__((ext_vector_type(8)));

__device__ __forceinline__ u16 f2bf(float f) {
    uint32_t u = __builtin_bit_cast(uint32_t, f);
    u += 0x7FFFu + ((u >> 16) & 1u);   // RNE, inputs finite
    return (u16)(u >> 16);
}

__device__ __forceinline__ void gload16(const void* g, void* l) {
    __builtin_amdgcn_global_load_lds(
        reinterpret_cast<const __attribute__((address_space(1))) void*>(reinterpret_cast<uintptr_t>(g)),
        reinterpret_cast<__attribute__((address_space(3))) void*>(reinterpret_cast<uintptr_t>(l)),
        16, 0, 0);
}

#define BAR() asm volatile("s_barrier" ::: "memory")

// ---------------------------------------------------------------------------
// GEMM: C[M,NN] = A[M,K] @ B[NN,K]^T (bf16, K-contiguous rows), K % 64 == 0.
// 256x256 tile, BK=64, 512 threads = 8 waves (2M x 4N), 128x64 per wave.
// 4 phases per K-tile (one 2x4-fragment C-quadrant each), counted vmcnt(6):
//   ph0: read B(all)+A(q0) of buf c; stage A(t+1)h1 -> buf c^1 (rows 64-127,192-255)
//   ph1: read A(q1); stage B(t+2)h0 -> buf c (B dead since ph0)
//   ph2: read A(q2); stage B(t+2)h1 -> buf c
//   ph3: read A(q3); stage A(t+2)h0 -> buf c (rows 0-63,128-191: q0+q1 dead)
//   each phase: [reads|stage] BAR ; setprio1 ; 16 MFMA ; setprio0 ; [ph3: vmcnt(6)] BAR
// Every stage targets a region whose last reader finished before a prior barrier.
// MODE 0: bf16 store C = f2bf(fw05[r,c>>10]*silu(acc+bias[c]))
// MODE 1: f32 store C = acc ; MODE 2: f32 C += acc
// ---------------------------------------------------------------------------
template <int MODE>
__global__ __launch_bounds__(512, 2)
void gemm256(const u16* __restrict__ A, int lda,
             const u16* __restrict__ B, int ldb, int K,
             void* __restrict__ Cout, int ldc,
             const float* __restrict__ bias, const float* __restrict__ fw05)
{
    __shared__ __align__(16) u16 As[2 * 256 * 64];
    __shared__ __align__(16) u16 Bs[2 * 256 * 64];

    const int t    = threadIdx.x;
    const int lane = t & 63;
    const int wave = t >> 6;
    const int l16  = lane & 15;
    const int lhi  = lane >> 4;
    const int wm   = wave >> 2;
    const int wn   = wave & 3;

    const size_t rowBase = (size_t)blockIdx.y * 256;
    const int    colBase = blockIdx.x * 256;
    const int    NT      = K >> 6;

    // staging: thread t covers 16B chunks (r*512 + t), r=0,1 -> row_local rl0, rl0+64
    const int rl0 = t >> 3;
    const int ko0 = (t & 7) * 8;

    const u16* aRow = A + (rowBase + rl0) * (size_t)lda + ko0;
    const u16* bRow = B + (size_t)(colBase + rl0) * ldb + ko0;
    u16* asW = As + rl0 * 64 + ko0;
    u16* bsW = Bs + rl0 * 64 + ko0;

#define STA(bufo, e, r0, r1)                                                     \
    do {                                                                         \
        gload16(aRow + (size_t)(r0) * lda + (e), asW + (bufo) + (r0) * 64);      \
        gload16(aRow + (size_t)(r1) * lda + (e), asW + (bufo) + (r1) * 64);      \
    } while (0)
#define STB(bufo, e, b0)                                                         \
    do {                                                                         \
        gload16(bRow + (size_t)(b0) * ldb + (e), bsW + (bufo) + (b0) * 64);      \
        gload16(bRow + (size_t)((b0) + 64) * ldb + (e),                          \
                bsW + (bufo) + ((b0) + 64) * 64);                                \
    } while (0)

    const u16* aRd = As + (wm * 128 + l16) * 64 + lhi * 8;
    const u16* bRd = Bs + (wn * 64 + l16) * 64 + lhi * 8;

    f32x4 acc[8][4];
#pragma unroll
    for (int i = 0; i < 8; i++)
#pragma unroll
        for (int j = 0; j < 4; j++)
            acc[i][j] = (f32x4){0.f, 0.f, 0.f, 0.f};

    // prologue: tile0 (4 half-tiles) -> buf0, then B1h0,B1h1,A1h0 -> buf1
    STA(0, 0, 0, 128);
    STA(0, 0, 64, 192);
    STB(0, 0, 0);
    STB(0, 0, 128);
    const int e1p = (NT > 1) ? 64 : 0;
    STB(16384, e1p, 0);
    STB(16384, e1p, 128);
    STA(16384, e1p, 0, 128);
    asm volatile("s_waitcnt vmcnt(6)" ::: "memory");   // tile0 landed; 3 half-tiles fly
    BAR();

    bf16x8 bfr[4][2];
    for (int tt = 0; tt < NT; ++tt) {
        const int c  = (tt & 1) << 14;
        const int cn = c ^ 16384;
        const int e1 = ((tt + 1 < NT) ? tt + 1 : NT - 1) << 6;
        const int e2 = ((tt + 2 < NT) ? tt + 2 : NT - 1) << 6;

#pragma unroll
        for (int q = 0; q < 4; ++q) {
            bf16x8 af[2][2];
#pragma unroll
            for (int s = 0; s < 2; ++s)
#pragma unroll
                for (int kk = 0; kk < 2; ++kk)
                    af[s][kk] = *(const bf16x8*)(aRd + c + (2 * q + s) * 16 * 64 + kk * 32);
            if (q == 0) {
#pragma unroll
                for (int ni = 0; ni < 4; ++ni)
#pragma unroll
                    for (int kk = 0; kk < 2; ++kk)
                        bfr[ni][kk] = *(const bf16x8*)(bRd + c + ni * 16 * 64 + kk * 32);
                STA(cn, e1, 64, 192);     // A(t+1) h1 -> other buffer
            } else if (q == 1) {
                STB(c, e2, 0);            // B(t+2) h0 -> active buffer (B dead)
            } else if (q == 2) {
                STB(c, e2, 128);          // B(t+2) h1
            } else {
                STA(c, e2, 0, 128);       // A(t+2) h0 (q0+q1 slices dead)
            }
            BAR();
            __builtin_amdgcn_s_setprio(1);
#pragma unroll
            for (int s = 0; s < 2; ++s)
#pragma unroll
                for (int ni = 0; ni < 4; ++ni)
#pragma unroll
                    for (int kk = 0; kk < 2; ++kk)
                        acc[2 * q + s][ni] = __builtin_amdgcn_mfma_f32_16x16x32_bf16(
                            af[s][kk], bfr[ni][kk], acc[2 * q + s][ni], 0, 0, 0);
            __builtin_amdgcn_s_setprio(0);
            if (q == 3) asm volatile("s_waitcnt vmcnt(6)" ::: "memory");
            BAR();
        }
    }

    const int orow = wm * 128 + lhi * 4;
    const int ocol = colBase + wn * 64 + l16;

    if constexpr (MODE == 0) {
        u16* C = (u16*)Cout;
#pragma unroll
        for (int mi = 0; mi < 8; mi++) {
#pragma unroll
            for (int j = 0; j < 4; j++) {
                size_t r = rowBase + orow + mi * 16 + j;
#pragma unroll
                for (int ni = 0; ni < 4; ni++) {
                    int cc = ocol + ni * 16;
                    float v = acc[mi][ni][j] + bias[cc];
                    float s = v / (1.f + __expf(-v));   // silu
                    C[r * (size_t)ldc + cc] = f2bf(fw05[r * 5 + (cc >> 10)] * s);
                }
            }
        }
    } else {
        float* C = (float*)Cout;
#pragma unroll
        for (int mi = 0; mi < 8; mi++) {
#pragma unroll
            for (int j = 0; j < 4; j++) {
                size_t r = rowBase + orow + mi * 16 + j;
#pragma unroll
                for (int ni = 0; ni < 4; ni++) {
                    size_t idx = r * (size_t)ldc + (ocol + ni * 16);
                    if constexpr (MODE == 1) C[idx] = acc[mi][ni][j];
                    else                     C[idx] += acc[mi][ni][j];
                }
            }
        }
    }
#undef STA
#undef STB
}

// ---------------------------------------------------------------------------
// Router: logits[r][0..79] = x[r] . {Wsoft(5) | Wsparse(5) | m_key(64) | Wg(5)}
// ---------------------------------------------------------------------------
__global__ __launch_bounds__(256)
void router_kernel(const float* __restrict__ x,
                   const float* __restrict__ Wsoft, const float* __restrict__ Wsparse,
                   const float* __restrict__ m_key, const float* __restrict__ Wg,
                   float* __restrict__ logits)
{
    __shared__ float Xs[128][66];
    __shared__ float Ws[80][132];

    const int t    = threadIdx.x;
    const int lane = t & 63;
    const int wave = t >> 6;
    const int row0 = blockIdx.x * 64;

    float acc[20];
#pragma unroll
    for (int c = 0; c < 20; c++) acc[c] = 0.f;

    for (int k0 = 0; k0 < 1024; k0 += 128) {
#pragma unroll
        for (int i = 0; i < 8; i++) {
            int f4 = i * 256 + t;
            int r  = f4 >> 5;
            int kk = (f4 & 31) * 4;
            f32x4 v = *(const f32x4*)(x + (size_t)(row0 + r) * 1024 + k0 + kk);
            Xs[kk + 0][r] = v[0]; Xs[kk + 1][r] = v[1];
            Xs[kk + 2][r] = v[2]; Xs[kk + 3][r] = v[3];
        }
#pragma unroll
        for (int i = 0; i < 10; i++) {
            int f4 = i * 256 + t;
            int j  = f4 >> 5;
            int kk = (f4 & 31) * 4;
            const float* src;
            if      (j < 5)  src = Wsoft   + (size_t)j * 1024;
            else if (j < 10) src = Wsparse + (size_t)(j - 5) * 1024;
            else if (j < 74) src = m_key   + (size_t)(j - 10) * 1024;
            else             src = Wg      + (size_t)(j - 74) * 1024;
            *(f32x4*)&Ws[j][kk] = *(const f32x4*)(src + k0 + kk);
        }
        __syncthreads();

        for (int k4 = 0; k4 < 32; k4++) {
            float x0 = Xs[k4 * 4 + 0][lane];
            float x1 = Xs[k4 * 4 + 1][lane];
            float x2 = Xs[k4 * 4 + 2][lane];
            float x3 = Xs[k4 * 4 + 3][lane];
#pragma unroll
            for (int c = 0; c < 20; c++) {
                f32x4 w = *(const f32x4*)&Ws[wave * 20 + c][k4 * 4];
                acc[c] += x0 * w[0] + x1 * w[1] + x2 * w[2] + x3 * w[3];
            }
        }
        __syncthreads();
    }

    float* dst = logits + (size_t)(row0 + lane) * 80 + wave * 20;
#pragma unroll
    for (int c = 0; c < 20; c++) dst[c] = acc[c];
}

// ---------------------------------------------------------------------------
__global__ __launch_bounds__(256)
void finalize_kernel(const float* __restrict__ logits, const float* __restrict__ m_val,
                     const float* __restrict__ bsoft, const float* __restrict__ bsparse,
                     const float* __restrict__ bg,
                     float* __restrict__ fw05, float* __restrict__ g05, int NC)
{
    __shared__ float mv[320];
    for (int i = threadIdx.x; i < 320; i += 256) mv[i] = m_val[i];
    __syncthreads();

    int idx = blockIdx.x * 256 + threadIdx.x;
    if (idx >= NC) return;
    const float* L = logits + (size_t)idx * 80;

    float sl[5];
#pragma unroll
    for (int e = 0; e < 5; e++) sl[e] = L[e] + bsoft[e];
    float sm = sl[0];
#pragma unroll
    for (int e = 1; e < 5; e++) sm = fmaxf(sm, sl[e]);
    float ssum = 0.f, sw[5];
#pragma unroll
    for (int e = 0; e < 5; e++) { sw[e] = __expf(sl[e] - sm); ssum += sw[e]; }
    float sinv = 1.f / ssum;

    int am = 0; float bv = L[5] + bsparse[0];
#pragma unroll
    for (int e = 1; e < 5; e++) {
        float v = L[5 + e] + bsparse[e];
        if (v > bv) { bv = v; am = e; }
    }

    float amax = -1e30f;
    for (int m = 0; m < 64; m++) amax = fmaxf(amax, L[10 + m] * 0.03125f);
    float asum = 0.f, mw[5] = {0.f, 0.f, 0.f, 0.f, 0.f};
    for (int m = 0; m < 64; m++) {
        float a = __expf(L[10 + m] * 0.03125f - amax);
        asum += a;
#pragma unroll
        for (int e = 0; e < 5; e++) mw[e] += a * mv[m * 5 + e];
    }
    float ainv = 1.f / asum;
#pragma unroll
    for (int e = 0; e < 5; e++) mw[e] *= ainv;
    float mm = mw[0];
#pragma unroll
    for (int e = 1; e < 5; e++) mm = fmaxf(mm, mw[e]);
    float msum = 0.f, me[5];
#pragma unroll
    for (int e = 0; e < 5; e++) { me[e] = __expf(mw[e] - mm); msum += me[e]; }
    float minv = 1.f / msum;

#pragma unroll
    for (int e = 0; e < 5; e++)
        fw05[(size_t)idx * 5 + e] =
            0.125f * ((e == am) ? 1.f : 0.f) + 0.125f * sw[e] * sinv + 0.25f * me[e] * minv;
#pragma unroll
    for (int q = 0; q < 5; q++)
        g05[(size_t)idx * 5 + q] = 0.5f / (1.f + __expf(-(L[74 + q] + bg[q])));
}

// ---------------------------------------------------------------------------
__global__ __launch_bounds__(256)
void cast_bf16_kernel(const float* __restrict__ src, u16* __restrict__ dst, size_t n)
{
    size_t i = ((size_t)blockIdx.x * 256 + threadIdx.x) * 8;
    if (i >= n) return;
    f32x4 a = *(const f32x4*)(src + i);
    f32x4 b = *(const f32x4*)(src + i + 4);
    ushort8 o;
    o[0] = f2bf(a[0]); o[1] = f2bf(a[1]); o[2] = f2bf(a[2]); o[3] = f2bf(a[3]);
    o[4] = f2bf(b[0]); o[5] = f2bf(b[1]); o[6] = f2bf(b[2]); o[7] = f2bf(b[3]);
    *(ushort8*)(dst + i) = o;
}

// W2cat[o][c], c<5120: W2[e][o][d]; c=5120+e (e<5): b2[e][o]; else 0. ld 5184.
__global__ __launch_bounds__(256)
void prep_w2cat(const float* __restrict__ W2, const float* __restrict__ b2,
                u16* __restrict__ out)
{
    size_t tid = (size_t)blockIdx.x * 256 + threadIdx.x;   // 1024*648
    int o  = (int)(tid / 648);
    int c0 = (int)(tid % 648) * 8;
    ushort8 v;
    if (c0 + 8 <= 5120) {
        int e = c0 >> 10, d = c0 & 1023;
        const float* s = W2 + ((size_t)e * 1024 + o) * 1024 + d;
        f32x4 a = *(const f32x4*)s;
        f32x4 b = *(const f32x4*)(s + 4);
        v[0] = f2bf(a[0]); v[1] = f2bf(a[1]); v[2] = f2bf(a[2]); v[3] = f2bf(a[3]);
        v[4] = f2bf(b[0]); v[5] = f2bf(b[1]); v[6] = f2bf(b[2]); v[7] = f2bf(b[3]);
    } else {
#pragma unroll
        for (int jj = 0; jj < 8; jj++) {
            int c = c0 + jj;
            float f = (c >= 5120 && c < 5125) ? b2[(size_t)(c - 5120) * 1024 + o] : 0.f;
            v[jj] = f2bf(f);
        }
    }
    *(ushort8*)(out + (size_t)o * 5184 + c0) = v;
}

// Wfcat[o][c], c<5120: Wf[o][c]; c==5120: bf[o]; else 0. ld 5184.
__global__ __launch_bounds__(256)
void prep_wfcat(const float* __restrict__ Wf, const float* __restrict__ bfias,
                u16* __restrict__ out)
{
    size_t tid = (size_t)blockIdx.x * 256 + threadIdx.x;   // 1024*648
    int o  = (int)(tid / 648);
    int c0 = (int)(tid % 648) * 8;
    ushort8 v;
    if (c0 + 8 <= 5120) {
        const float* s = Wf + (size_t)o * 5120 + c0;
        f32x4 a = *(const f32x4*)s;
        f32x4 b = *(const f32x4*)(s + 4);
        v[0] = f2bf(a[0]); v[1] = f2bf(a[1]); v[2] = f2bf(a[2]); v[3] = f2bf(a[3]);
        v[4] = f2bf(b[0]); v[5] = f2bf(b[1]); v[6] = f2bf(b[2]); v[7] = f2bf(b[3]);
    } else {
#pragma unroll
        for (int jj = 0; jj < 8; jj++) {
            int c = c0 + jj;
            v[jj] = f2bf((c == 5120) ? bfias[o] : 0.f);
        }
    }
    *(ushort8*)(out + (size_t)o * 5184 + c0) = v;
}

// Abuf[r][c] = bf16(g05[r,q] * feat_q[r][d]) for c<5120; ld 5184.
__global__ __launch_bounds__(256)
void build_afused(const float* __restrict__ f0, const float* __restrict__ f1,
                  const float* __restrict__ f2, const float* __restrict__ f3,
                  const float* __restrict__ f4,
                  const float* __restrict__ g05, u16* __restrict__ Abuf)
{
    size_t tid = (size_t)blockIdx.x * 256 + threadIdx.x;   // NC*640
    size_t r  = tid / 640;
    int   c0  = (int)(tid % 640) * 8;
    int   q   = c0 >> 10;
    int   d   = c0 & 1023;
    const float* fq = (q == 0) ? f0 : (q == 1) ? f1 : (q == 2) ? f2 : (q == 3) ? f3 : f4;
    float g = g05[r * 5 + q];
    f32x4 a = *(const f32x4*)(fq + r * 1024 + d);
    f32x4 b = *(const f32x4*)(fq + r * 1024 + d + 4);
    ushort8 v;
    v[0] = f2bf(g * a[0]); v[1] = f2bf(g * a[1]); v[2] = f2bf(g * a[2]); v[3] = f2bf(g * a[3]);
    v[4] = f2bf(g * b[0]); v[5] = f2bf(g * b[1]); v[6] = f2bf(g * b[2]); v[7] = f2bf(g * b[3]);
    *(ushort8*)(Abuf + r * 5184 + c0) = v;
}

// Tail cols 5120..5183. mode 0: fw05[r,e] at 5120+e. mode 1: 0.5 at 5120.
__global__ __launch_bounds__(256)
void fill_tail(const float* __restrict__ fw05, u16* __restrict__ Abuf, int NC, int mode)
{
    int r = blockIdx.x * 256 + threadIdx.x;
    if (r >= NC) return;
    u16* dst = Abuf + (size_t)r * 5184 + 5120;
    if (mode == 0) {
#pragma unroll
        for (int e = 0; e < 5; e++) dst[e] = f2bf(fw05[(size_t)r * 5 + e]);
        for (int j = 5; j < 64; j++) dst[j] = 0;
    } else {
        dst[0] = f2bf(0.5f);
        for (int j = 1; j < 64; j++) dst[j] = 0;
    }
}

// ---------------------------------------------------------------------------
extern "C" void kernel_launch(void* const* d_in, const int* in_sizes, int n_in,
                              void* d_out, int out_size, void* d_ws, size_t ws_size,
                              hipStream_t stream)
{
    (void)in_sizes; (void)n_in; (void)out_size;

    const float* x      = (const float*)d_in[0];
    const float* spect  = (const float*)d_in[1];
    const float* wavef  = (const float*)d_in[2];
    const float* pitch  = (const float*)d_in[3];
    const float* envel  = (const float*)d_in[4];
    const float* phase  = (const float*)d_in[5];
    const float* Wsoft  = (const float*)d_in[6];
    const float* bsoft  = (const float*)d_in[7];
    const float* Wsparse= (const float*)d_in[8];
    const float* bsparse= (const float*)d_in[9];
    const float* m_key  = (const float*)d_in[10];
    const float* m_val  = (const float*)d_in[11];
    const float* W1     = (const float*)d_in[12];
    const float* b1     = (const float*)d_in[13];
    const float* W2     = (const float*)d_in[14];
    const float* b2     = (const float*)d_in[15];
    const float* Wg     = (const float*)d_in[16];
    const float* bg     = (const float*)d_in[17];
    const float* Wf     = (const float*)d_in[18];
    const float* bfias  = (const float*)d_in[19];
    float* out = (float*)d_out;

    const int N = 16384;

    // workspace layout (per-row: 2048 Xbf + 10368 Abuf + 320 logits + 40)
    size_t fixed = (size_t)5 * 1024 * 1024 * 2 + 2 * (size_t)1024 * 5184 * 2;
    int NC = 16384;
    while (NC > 256 && fixed + (size_t)NC * 12776 > ws_size) NC >>= 1;

    char* p = (char*)d_ws;
    u16* W1bf  = (u16*)p; p += (size_t)5 * 1024 * 1024 * 2;
    u16* W2cat = (u16*)p; p += (size_t)1024 * 5184 * 2;
    u16* Wfcat = (u16*)p; p += (size_t)1024 * 5184 * 2;
    u16* Xbf   = (u16*)p; p += (size_t)NC * 1024 * 2;
    u16* Abuf  = (u16*)p; p += (size_t)NC * 5184 * 2;
    float* logits = (float*)p; p += (size_t)NC * 80 * 4;
    float* fw05   = (float*)p; p += (size_t)NC * 5 * 4;
    float* g05    = (float*)p; p += (size_t)NC * 5 * 4;

    // one-time weight prep (W1 flat IS W1cat[5120][1024]: row e*1024+o)
    cast_bf16_kernel<<<2560, 256, 0, stream>>>(W1, W1bf, (size_t)5 * 1024 * 1024);
    prep_w2cat<<<2592, 256, 0, stream>>>(W2, b2, W2cat);
    prep_wfcat<<<2592, 256, 0, stream>>>(Wf, bfias, Wfcat);

    for (int n0 = 0; n0 < N; n0 += NC) {
        const float* xc = x + (size_t)n0 * 1024;

        router_kernel<<<NC / 64, 256, 0, stream>>>(xc, Wsoft, Wsparse, m_key, Wg, logits);
        finalize_kernel<<<(NC + 255) / 256, 256, 0, stream>>>(logits, m_val, bsoft, bsparse, bg,
                                                              fw05, g05, NC);
        cast_bf16_kernel<<<NC / 2, 256, 0, stream>>>(xc, Xbf, (size_t)NC * 1024);

        // all experts in one GEMM: Abuf[:,0:5120] = fw05_e * silu(X @ W1^T + b1)
        gemm256<0><<<dim3(20, NC / 256), 512, 0, stream>>>(
            Xbf, 1024, W1bf, 1024, 1024, Abuf, 5184, b1, fw05);
        fill_tail<<<(NC + 255) / 256, 256, 0, stream>>>(fw05, Abuf, NC, 0);

        // 0.5*moe -> out
        gemm256<1><<<dim3(4, NC / 256), 512, 0, stream>>>(
            Abuf, 5184, W2cat, 5184, 5184, out + (size_t)n0 * 1024, 1024, nullptr, nullptr);

        // gated features -> Abuf, then out += 0.5*fused
        build_afused<<<(unsigned)((size_t)NC * 640 / 256), 256, 0, stream>>>(
            spect + (size_t)n0 * 1024, wavef + (size_t)n0 * 1024,
            pitch + (size_t)n0 * 1024, envel + (size_t)n0 * 1024,
            phase + (size_t)n0 * 1024, g05, Abuf);
        fill_tail<<<(NC + 255) / 256, 256, 0, stream>>>(fw05, Abuf, NC, 1);

        gemm256<2><<<dim3(4, NC / 256), 512, 0, stream>>>(
            Abuf, 5184, Wfcat, 5184, 5184, out + (size_t)n0 * 1024, 1024, nullptr, nullptr);
    }
}

// Round 3
// 746.979 us; speedup vs baseline: 1.7810x; 1.1391x over previous
//
#include <hip/hip_runtime.h>
#include <stdint.h>

typedef __bf16 bf16x8 __attribute__((ext_vector_type(8)));
typedef float f32x4 __attribute__((ext_vector_type(4)));
typedef unsigned short u16;
typedef u16 ushort8 __attribute__((ext_vector_type(8)));

__device__ __forceinline__ u16 f2bf(float f) {
    uint32_t u = __builtin_bit_cast(uint32_t, f);
    u += 0x7FFFu + ((u >> 16) & 1u);   // RNE, inputs finite
    return (u16)(u >> 16);
}

__device__ __forceinline__ void gload16(const void* g, void* l) {
    __builtin_amdgcn_global_load_lds(
        reinterpret_cast<const __attribute__((address_space(1))) void*>(reinterpret_cast<uintptr_t>(g)),
        reinterpret_cast<__attribute__((address_space(3))) void*>(reinterpret_cast<uintptr_t>(l)),
        16, 0, 0);
}

#define BAR() asm volatile("s_barrier" ::: "memory")

// ---------------------------------------------------------------------------
// GEMM: C[M,NN] = A[M,K] @ B[NN,K]^T (bf16, K-contiguous rows), K % 64 == 0.
// 256x256 tile, BK=64, 512 threads = 8 waves (2M x 4N), 128x64 per wave.
// LDS XOR-swizzle (T2, rule #21): content at (row, phys_chunk p) = global
// (row, p ^ (row&7)); staging pre-swizzles the GLOBAL source chunk (LDS dest
// stays linear, as global_load_lds requires), reads XOR the chunk index.
// 4 phases per K-tile, counted vmcnt(6) (T3+T4), setprio around MFMA (T5).
// MODE 0: bf16 store C = f2bf(fw05[r,c>>10]*silu(acc+bias[c]))
// MODE 1: f32 store C = acc ; MODE 2: f32 C += acc
// ---------------------------------------------------------------------------
template <int MODE>
__global__ __launch_bounds__(512, 2)
void gemm256(const u16* __restrict__ A, int lda,
             const u16* __restrict__ B, int ldb, int K,
             void* __restrict__ Cout, int ldc,
             const float* __restrict__ bias, const float* __restrict__ fw05)
{
    __shared__ __align__(16) u16 As[2 * 256 * 64];
    __shared__ __align__(16) u16 Bs[2 * 256 * 64];

    const int t    = threadIdx.x;
    const int lane = t & 63;
    const int wave = t >> 6;
    const int l16  = lane & 15;
    const int lhi  = lane >> 4;
    const int wm   = wave >> 2;
    const int wn   = wave & 3;

    const size_t rowBase = (size_t)blockIdx.y * 256;
    const int    colBase = blockIdx.x * 256;
    const int    NT      = K >> 6;

    // staging: thread t -> LDS row rl0 (+64/128/192), phys chunk t&7 (linear);
    // global source chunk = (t&7) ^ (rl0&7). Row offsets are multiples of 64,
    // so (row&7) is invariant across the 4 sub-loads of one thread.
    const int rl0 = t >> 3;
    const int ko0 = (t & 7) * 8;                       // linear LDS chunk (dest)
    const int kos = ((t & 7) ^ (rl0 & 7)) * 8;         // swizzled global chunk (src)

    const u16* aRow = A + (rowBase + rl0) * (size_t)lda + kos;
    const u16* bRow = B + (size_t)(colBase + rl0) * ldb + kos;
    u16* asW = As + rl0 * 64 + ko0;
    u16* bsW = Bs + rl0 * 64 + ko0;

#define STA(bufo, e, r0, r1)                                                     \
    do {                                                                         \
        gload16(aRow + (size_t)(r0) * lda + (e), asW + (bufo) + (r0) * 64);      \
        gload16(aRow + (size_t)(r1) * lda + (e), asW + (bufo) + (r1) * 64);      \
    } while (0)
#define STB(bufo, e, b0)                                                         \
    do {                                                                         \
        gload16(bRow + (size_t)(b0) * ldb + (e), bsW + (bufo) + (b0) * 64);      \
        gload16(bRow + (size_t)((b0) + 64) * ldb + (e),                          \
                bsW + (bufo) + ((b0) + 64) * 64);                                \
    } while (0)

    // fragment reads: row = base + l16 (+16-multiples), so row&7 = l16&7;
    // logical chunk lhi (kk=0) / lhi+4 (kk=1) -> phys chunk ^ (l16&7).
    const int sw = l16 & 7;
    const u16* aRd0 = As + (wm * 128 + l16) * 64 + ((lhi ^ sw) * 8);
    const u16* aRd1 = As + (wm * 128 + l16) * 64 + (((lhi + 4) ^ sw) * 8);
    const u16* bRd0 = Bs + (wn * 64 + l16) * 64 + ((lhi ^ sw) * 8);
    const u16* bRd1 = Bs + (wn * 64 + l16) * 64 + (((lhi + 4) ^ sw) * 8);

    f32x4 acc[8][4];
#pragma unroll
    for (int i = 0; i < 8; i++)
#pragma unroll
        for (int j = 0; j < 4; j++)
            acc[i][j] = (f32x4){0.f, 0.f, 0.f, 0.f};

    // prologue: tile0 (4 half-tiles) -> buf0, then B1h0,B1h1,A1h0 -> buf1
    STA(0, 0, 0, 128);
    STA(0, 0, 64, 192);
    STB(0, 0, 0);
    STB(0, 0, 128);
    const int e1p = (NT > 1) ? 64 : 0;
    STB(16384, e1p, 0);
    STB(16384, e1p, 128);
    STA(16384, e1p, 0, 128);
    asm volatile("s_waitcnt vmcnt(6)" ::: "memory");   // tile0 landed; 3 half-tiles fly
    BAR();

    bf16x8 bfr[4][2];
    for (int tt = 0; tt < NT; ++tt) {
        const int c  = (tt & 1) << 14;
        const int cn = c ^ 16384;
        const int e1 = ((tt + 1 < NT) ? tt + 1 : NT - 1) << 6;
        const int e2 = ((tt + 2 < NT) ? tt + 2 : NT - 1) << 6;

#pragma unroll
        for (int q = 0; q < 4; ++q) {
            bf16x8 af[2][2];
#pragma unroll
            for (int s = 0; s < 2; ++s) {
                af[s][0] = *(const bf16x8*)(aRd0 + c + (2 * q + s) * 16 * 64);
                af[s][1] = *(const bf16x8*)(aRd1 + c + (2 * q + s) * 16 * 64);
            }
            if (q == 0) {
#pragma unroll
                for (int ni = 0; ni < 4; ++ni) {
                    bfr[ni][0] = *(const bf16x8*)(bRd0 + c + ni * 16 * 64);
                    bfr[ni][1] = *(const bf16x8*)(bRd1 + c + ni * 16 * 64);
                }
                STA(cn, e1, 64, 192);     // A(t+1) h1 -> other buffer
            } else if (q == 1) {
                STB(c, e2, 0);            // B(t+2) h0 -> active buffer (B dead)
            } else if (q == 2) {
                STB(c, e2, 128);          // B(t+2) h1
            } else {
                STA(c, e2, 0, 128);       // A(t+2) h0 (q0+q1 slices dead)
            }
            BAR();
            __builtin_amdgcn_s_setprio(1);
#pragma unroll
            for (int s = 0; s < 2; ++s)
#pragma unroll
                for (int ni = 0; ni < 4; ++ni)
#pragma unroll
                    for (int kk = 0; kk < 2; ++kk)
                        acc[2 * q + s][ni] = __builtin_amdgcn_mfma_f32_16x16x32_bf16(
                            af[s][kk], bfr[ni][kk], acc[2 * q + s][ni], 0, 0, 0);
            __builtin_amdgcn_s_setprio(0);
            if (q == 3) asm volatile("s_waitcnt vmcnt(6)" ::: "memory");
            BAR();
        }
    }

    const int orow = wm * 128 + lhi * 4;
    const int ocol = colBase + wn * 64 + l16;

    if constexpr (MODE == 0) {
        u16* C = (u16*)Cout;
#pragma unroll
        for (int mi = 0; mi < 8; mi++) {
#pragma unroll
            for (int j = 0; j < 4; j++) {
                size_t r = rowBase + orow + mi * 16 + j;
#pragma unroll
                for (int ni = 0; ni < 4; ni++) {
                    int cc = ocol + ni * 16;
                    float v = acc[mi][ni][j] + bias[cc];
                    float s = v / (1.f + __expf(-v));   // silu
                    C[r * (size_t)ldc + cc] = f2bf(fw05[r * 5 + (cc >> 10)] * s);
                }
            }
        }
    } else {
        float* C = (float*)Cout;
#pragma unroll
        for (int mi = 0; mi < 8; mi++) {
#pragma unroll
            for (int j = 0; j < 4; j++) {
                size_t r = rowBase + orow + mi * 16 + j;
#pragma unroll
                for (int ni = 0; ni < 4; ni++) {
                    size_t idx = r * (size_t)ldc + (ocol + ni * 16);
                    if constexpr (MODE == 1) C[idx] = acc[mi][ni][j];
                    else                     C[idx] += acc[mi][ni][j];
                }
            }
        }
    }
#undef STA
#undef STB
}

// ---------------------------------------------------------------------------
// Router: logits[r][0..79] = x[r] . {Wsoft(5) | Wsparse(5) | m_key(64) | Wg(5)}
// ---------------------------------------------------------------------------
__global__ __launch_bounds__(256)
void router_kernel(const float* __restrict__ x,
                   const float* __restrict__ Wsoft, const float* __restrict__ Wsparse,
                   const float* __restrict__ m_key, const float* __restrict__ Wg,
                   float* __restrict__ logits)
{
    __shared__ float Xs[128][66];
    __shared__ float Ws[80][132];

    const int t    = threadIdx.x;
    const int lane = t & 63;
    const int wave = t >> 6;
    const int row0 = blockIdx.x * 64;

    float acc[20];
#pragma unroll
    for (int c = 0; c < 20; c++) acc[c] = 0.f;

    for (int k0 = 0; k0 < 1024; k0 += 128) {
#pragma unroll
        for (int i = 0; i < 8; i++) {
            int f4 = i * 256 + t;
            int r  = f4 >> 5;
            int kk = (f4 & 31) * 4;
            f32x4 v = *(const f32x4*)(x + (size_t)(row0 + r) * 1024 + k0 + kk);
            Xs[kk + 0][r] = v[0]; Xs[kk + 1][r] = v[1];
            Xs[kk + 2][r] = v[2]; Xs[kk + 3][r] = v[3];
        }
#pragma unroll
        for (int i = 0; i < 10; i++) {
            int f4 = i * 256 + t;
            int j  = f4 >> 5;
            int kk = (f4 & 31) * 4;
            const float* src;
            if      (j < 5)  src = Wsoft   + (size_t)j * 1024;
            else if (j < 10) src = Wsparse + (size_t)(j - 5) * 1024;
            else if (j < 74) src = m_key   + (size_t)(j - 10) * 1024;
            else             src = Wg      + (size_t)(j - 74) * 1024;
            *(f32x4*)&Ws[j][kk] = *(const f32x4*)(src + k0 + kk);
        }
        __syncthreads();

        for (int k4 = 0; k4 < 32; k4++) {
            float x0 = Xs[k4 * 4 + 0][lane];
            float x1 = Xs[k4 * 4 + 1][lane];
            float x2 = Xs[k4 * 4 + 2][lane];
            float x3 = Xs[k4 * 4 + 3][lane];
#pragma unroll
            for (int c = 0; c < 20; c++) {
                f32x4 w = *(const f32x4*)&Ws[wave * 20 + c][k4 * 4];
                acc[c] += x0 * w[0] + x1 * w[1] + x2 * w[2] + x3 * w[3];
            }
        }
        __syncthreads();
    }

    float* dst = logits + (size_t)(row0 + lane) * 80 + wave * 20;
#pragma unroll
    for (int c = 0; c < 20; c++) dst[c] = acc[c];
}

// ---------------------------------------------------------------------------
__global__ __launch_bounds__(256)
void finalize_kernel(const float* __restrict__ logits, const float* __restrict__ m_val,
                     const float* __restrict__ bsoft, const float* __restrict__ bsparse,
                     const float* __restrict__ bg,
                     float* __restrict__ fw05, float* __restrict__ g05, int NC)
{
    __shared__ float mv[320];
    for (int i = threadIdx.x; i < 320; i += 256) mv[i] = m_val[i];
    __syncthreads();

    int idx = blockIdx.x * 256 + threadIdx.x;
    if (idx >= NC) return;
    const float* L = logits + (size_t)idx * 80;

    float sl[5];
#pragma unroll
    for (int e = 0; e < 5; e++) sl[e] = L[e] + bsoft[e];
    float sm = sl[0];
#pragma unroll
    for (int e = 1; e < 5; e++) sm = fmaxf(sm, sl[e]);
    float ssum = 0.f, sw[5];
#pragma unroll
    for (int e = 0; e < 5; e++) { sw[e] = __expf(sl[e] - sm); ssum += sw[e]; }
    float sinv = 1.f / ssum;

    int am = 0; float bv = L[5] + bsparse[0];
#pragma unroll
    for (int e = 1; e < 5; e++) {
        float v = L[5 + e] + bsparse[e];
        if (v > bv) { bv = v; am = e; }
    }

    float amax = -1e30f;
    for (int m = 0; m < 64; m++) amax = fmaxf(amax, L[10 + m] * 0.03125f);
    float asum = 0.f, mw[5] = {0.f, 0.f, 0.f, 0.f, 0.f};
    for (int m = 0; m < 64; m++) {
        float a = __expf(L[10 + m] * 0.03125f - amax);
        asum += a;
#pragma unroll
        for (int e = 0; e < 5; e++) mw[e] += a * mv[m * 5 + e];
    }
    float ainv = 1.f / asum;
#pragma unroll
    for (int e = 0; e < 5; e++) mw[e] *= ainv;
    float mm = mw[0];
#pragma unroll
    for (int e = 1; e < 5; e++) mm = fmaxf(mm, mw[e]);
    float msum = 0.f, me[5];
#pragma unroll
    for (int e = 0; e < 5; e++) { me[e] = __expf(mw[e] - mm); msum += me[e]; }
    float minv = 1.f / msum;

#pragma unroll
    for (int e = 0; e < 5; e++)
        fw05[(size_t)idx * 5 + e] =
            0.125f * ((e == am) ? 1.f : 0.f) + 0.125f * sw[e] * sinv + 0.25f * me[e] * minv;
#pragma unroll
    for (int q = 0; q < 5; q++)
        g05[(size_t)idx * 5 + q] = 0.5f / (1.f + __expf(-(L[74 + q] + bg[q])));
}

// ---------------------------------------------------------------------------
__global__ __launch_bounds__(256)
void cast_bf16_kernel(const float* __restrict__ src, u16* __restrict__ dst, size_t n)
{
    size_t i = ((size_t)blockIdx.x * 256 + threadIdx.x) * 8;
    if (i >= n) return;
    f32x4 a = *(const f32x4*)(src + i);
    f32x4 b = *(const f32x4*)(src + i + 4);
    ushort8 o;
    o[0] = f2bf(a[0]); o[1] = f2bf(a[1]); o[2] = f2bf(a[2]); o[3] = f2bf(a[3]);
    o[4] = f2bf(b[0]); o[5] = f2bf(b[1]); o[6] = f2bf(b[2]); o[7] = f2bf(b[3]);
    *(ushort8*)(dst + i) = o;
}

// W2cat[o][c], c<5120: W2[e][o][d]; c=5120+e (e<5): b2[e][o]; else 0. ld 5184.
__global__ __launch_bounds__(256)
void prep_w2cat(const float* __restrict__ W2, const float* __restrict__ b2,
                u16* __restrict__ out)
{
    size_t tid = (size_t)blockIdx.x * 256 + threadIdx.x;   // 1024*648
    int o  = (int)(tid / 648);
    int c0 = (int)(tid % 648) * 8;
    ushort8 v;
    if (c0 + 8 <= 5120) {
        int e = c0 >> 10, d = c0 & 1023;
        const float* s = W2 + ((size_t)e * 1024 + o) * 1024 + d;
        f32x4 a = *(const f32x4*)s;
        f32x4 b = *(const f32x4*)(s + 4);
        v[0] = f2bf(a[0]); v[1] = f2bf(a[1]); v[2] = f2bf(a[2]); v[3] = f2bf(a[3]);
        v[4] = f2bf(b[0]); v[5] = f2bf(b[1]); v[6] = f2bf(b[2]); v[7] = f2bf(b[3]);
    } else {
#pragma unroll
        for (int jj = 0; jj < 8; jj++) {
            int c = c0 + jj;
            float f = (c >= 5120 && c < 5125) ? b2[(size_t)(c - 5120) * 1024 + o] : 0.f;
            v[jj] = f2bf(f);
        }
    }
    *(ushort8*)(out + (size_t)o * 5184 + c0) = v;
}

// Wfcat[o][c], c<5120: Wf[o][c]; c==5120: bf[o]; else 0. ld 5184.
__global__ __launch_bounds__(256)
void prep_wfcat(const float* __restrict__ Wf, const float* __restrict__ bfias,
                u16* __restrict__ out)
{
    size_t tid = (size_t)blockIdx.x * 256 + threadIdx.x;   // 1024*648
    int o  = (int)(tid / 648);
    int c0 = (int)(tid % 648) * 8;
    ushort8 v;
    if (c0 + 8 <= 5120) {
        const float* s = Wf + (size_t)o * 5120 + c0;
        f32x4 a = *(const f32x4*)s;
        f32x4 b = *(const f32x4*)(s + 4);
        v[0] = f2bf(a[0]); v[1] = f2bf(a[1]); v[2] = f2bf(a[2]); v[3] = f2bf(a[3]);
        v[4] = f2bf(b[0]); v[5] = f2bf(b[1]); v[6] = f2bf(b[2]); v[7] = f2bf(b[3]);
    } else {
#pragma unroll
        for (int jj = 0; jj < 8; jj++) {
            int c = c0 + jj;
            v[jj] = f2bf((c == 5120) ? bfias[o] : 0.f);
        }
    }
    *(ushort8*)(out + (size_t)o * 5184 + c0) = v;
}

// Abuf[r][c] = bf16(g05[r,q] * feat_q[r][d]) for c<5120; ld 5184.
__global__ __launch_bounds__(256)
void build_afused(const float* __restrict__ f0, const float* __restrict__ f1,
                  const float* __restrict__ f2, const float* __restrict__ f3,
                  const float* __restrict__ f4,
                  const float* __restrict__ g05, u16* __restrict__ Abuf)
{
    size_t tid = (size_t)blockIdx.x * 256 + threadIdx.x;   // NC*640
    size_t r  = tid / 640;
    int   c0  = (int)(tid % 640) * 8;
    int   q   = c0 >> 10;
    int   d   = c0 & 1023;
    const float* fq = (q == 0) ? f0 : (q == 1) ? f1 : (q == 2) ? f2 : (q == 3) ? f3 : f4;
    float g = g05[r * 5 + q];
    f32x4 a = *(const f32x4*)(fq + r * 1024 + d);
    f32x4 b = *(const f32x4*)(fq + r * 1024 + d + 4);
    ushort8 v;
    v[0] = f2bf(g * a[0]); v[1] = f2bf(g * a[1]); v[2] = f2bf(g * a[2]); v[3] = f2bf(g * a[3]);
    v[4] = f2bf(g * b[0]); v[5] = f2bf(g * b[1]); v[6] = f2bf(g * b[2]); v[7] = f2bf(g * b[3]);
    *(ushort8*)(Abuf + r * 5184 + c0) = v;
}

// Tail cols 5120..5183. mode 0: fw05[r,e] at 5120+e. mode 1: 0.5 at 5120.
__global__ __launch_bounds__(256)
void fill_tail(const float* __restrict__ fw05, u16* __restrict__ Abuf, int NC, int mode)
{
    int r = blockIdx.x * 256 + threadIdx.x;
    if (r >= NC) return;
    u16* dst = Abuf + (size_t)r * 5184 + 5120;
    if (mode == 0) {
#pragma unroll
        for (int e = 0; e < 5; e++) dst[e] = f2bf(fw05[(size_t)r * 5 + e]);
        for (int j = 5; j < 64; j++) dst[j] = 0;
    } else {
        dst[0] = f2bf(0.5f);
        for (int j = 1; j < 64; j++) dst[j] = 0;
    }
}

// ---------------------------------------------------------------------------
extern "C" void kernel_launch(void* const* d_in, const int* in_sizes, int n_in,
                              void* d_out, int out_size, void* d_ws, size_t ws_size,
                              hipStream_t stream)
{
    (void)in_sizes; (void)n_in; (void)out_size;

    const float* x      = (const float*)d_in[0];
    const float* spect  = (const float*)d_in[1];
    const float* wavef  = (const float*)d_in[2];
    const float* pitch  = (const float*)d_in[3];
    const float* envel  = (const float*)d_in[4];
    const float* phase  = (const float*)d_in[5];
    const float* Wsoft  = (const float*)d_in[6];
    const float* bsoft  = (const float*)d_in[7];
    const float* Wsparse= (const float*)d_in[8];
    const float* bsparse= (const float*)d_in[9];
    const float* m_key  = (const float*)d_in[10];
    const float* m_val  = (const float*)d_in[11];
    const float* W1     = (const float*)d_in[12];
    const float* b1     = (const float*)d_in[13];
    const float* W2     = (const float*)d_in[14];
    const float* b2     = (const float*)d_in[15];
    const float* Wg     = (const float*)d_in[16];
    const float* bg     = (const float*)d_in[17];
    const float* Wf     = (const float*)d_in[18];
    const float* bfias  = (const float*)d_in[19];
    float* out = (float*)d_out;

    const int N = 16384;

    // workspace layout (per-row: 2048 Xbf + 10368 Abuf + 320 logits + 40)
    size_t fixed = (size_t)5 * 1024 * 1024 * 2 + 2 * (size_t)1024 * 5184 * 2;
    int NC = 16384;
    while (NC > 256 && fixed + (size_t)NC * 12776 > ws_size) NC >>= 1;

    char* p = (char*)d_ws;
    u16* W1bf  = (u16*)p; p += (size_t)5 * 1024 * 1024 * 2;
    u16* W2cat = (u16*)p; p += (size_t)1024 * 5184 * 2;
    u16* Wfcat = (u16*)p; p += (size_t)1024 * 5184 * 2;
    u16* Xbf   = (u16*)p; p += (size_t)NC * 1024 * 2;
    u16* Abuf  = (u16*)p; p += (size_t)NC * 5184 * 2;
    float* logits = (float*)p; p += (size_t)NC * 80 * 4;
    float* fw05   = (float*)p; p += (size_t)NC * 5 * 4;
    float* g05    = (float*)p; p += (size_t)NC * 5 * 4;

    // one-time weight prep (W1 flat IS W1cat[5120][1024]: row e*1024+o)
    cast_bf16_kernel<<<2560, 256, 0, stream>>>(W1, W1bf, (size_t)5 * 1024 * 1024);
    prep_w2cat<<<2592, 256, 0, stream>>>(W2, b2, W2cat);
    prep_wfcat<<<2592, 256, 0, stream>>>(Wf, bfias, Wfcat);

    for (int n0 = 0; n0 < N; n0 += NC) {
        const float* xc = x + (size_t)n0 * 1024;

        router_kernel<<<NC / 64, 256, 0, stream>>>(xc, Wsoft, Wsparse, m_key, Wg, logits);
        finalize_kernel<<<(NC + 255) / 256, 256, 0, stream>>>(logits, m_val, bsoft, bsparse, bg,
                                                              fw05, g05, NC);
        cast_bf16_kernel<<<NC / 2, 256, 0, stream>>>(xc, Xbf, (size_t)NC * 1024);

        // all experts in one GEMM: Abuf[:,0:5120] = fw05_e * silu(X @ W1^T + b1)
        gemm256<0><<<dim3(20, NC / 256), 512, 0, stream>>>(
            Xbf, 1024, W1bf, 1024, 1024, Abuf, 5184, b1, fw05);
        fill_tail<<<(NC + 255) / 256, 256, 0, stream>>>(fw05, Abuf, NC, 0);

        // 0.5*moe -> out
        gemm256<1><<<dim3(4, NC / 256), 512, 0, stream>>>(
            Abuf, 5184, W2cat, 5184, 5184, out + (size_t)n0 * 1024, 1024, nullptr, nullptr);

        // gated features -> Abuf, then out += 0.5*fused
        build_afused<<<(unsigned)((size_t)NC * 640 / 256), 256, 0, stream>>>(
            spect + (size_t)n0 * 1024, wavef + (size_t)n0 * 1024,
            pitch + (size_t)n0 * 1024, envel + (size_t)n0 * 1024,
            phase + (size_t)n0 * 1024, g05, Abuf);
        fill_tail<<<(NC + 255) / 256, 256, 0, stream>>>(fw05, Abuf, NC, 1);

        gemm256<2><<<dim3(4, NC / 256), 512, 0, stream>>>(
            Abuf, 5184, Wfcat, 5184, 5184, out + (size_t)n0 * 1024, 1024, nullptr, nullptr);
    }
}